// Round 2
// baseline (260.911 us; speedup 1.0000x reference)
//
#include <hip/hip_runtime.h>
#include <stdint.h>

// Lovasz-softmax loss without sorting:
//   loss_c = sum over descending error levels v of v * (J(n>=v, f>=v) - J_prev)
// where n(v)=#{err_c >= v}, f(v)=#{label==c and err_c >= v},
//   J(n,f) = 1 - (G - f) / (G + n - f), G = #{label==c}.
// Tie-grouping is exact; quantizing errors to 768 bins perturbs loss by
// <= 2 * 0.5/767 ~= 1.3e-3 (threshold 1.9e-2; measured absmax 0.0 in R1).
//
// R2 structure: memset(934KB) -> k1 (softmax+LDS hist, global-atomic flush
// into 8 partial histograms) -> k2 (single-block scan + final average).

#define C_CLASSES 19
#define NBINS 768
#define HISTWORDS (C_CLASSES * NBINS)   // 14592
#define HW_SHIFT 18                     // H*W = 512*512 = 2^18
#define HW_MASK ((1 << HW_SHIFT) - 1)
#define NGROUPS 8

// K1: fused softmax + error histogram. Packed LDS counters:
// low 16 = n count, high 16 = fg count (per-block counts <= 4096 < 2^16).
// Flush: global atomicAdd into group (blockIdx & 7) of the partial hists.
__global__ __launch_bounds__(1024) void k1_hist(
    const float* __restrict__ x, const int* __restrict__ labels,
    int* __restrict__ nGlob, int* __restrict__ fGlob, int P, int pixPerBlk)
{
    __shared__ unsigned int hist[HISTWORDS];   // 58368 B
    int tid = threadIdx.x;
    for (int i = tid; i < HISTWORDS; i += 1024) hist[i] = 0u;
    __syncthreads();

    int base = blockIdx.x * pixPerBlk;
    for (int it = 0; it < pixPerBlk; it += 1024) {
        int p = base + it + tid;
        if (p < P) {
            int lab = labels[p];
            int img = p >> HW_SHIFT;
            int rem = p & HW_MASK;
            const float* xp = x + (((size_t)img * C_CLASSES) << HW_SHIFT) + rem;
            float r[C_CLASSES];
            float m = -1e30f;
#pragma unroll
            for (int c = 0; c < C_CLASSES; ++c) {
                r[c] = xp[(size_t)c << HW_SHIFT];
                m = fmaxf(m, r[c]);
            }
            float s = 0.f;
#pragma unroll
            for (int c = 0; c < C_CLASSES; ++c) { r[c] = __expf(r[c] - m); s += r[c]; }
            float inv = 1.f / s;
#pragma unroll
            for (int c = 0; c < C_CLASSES; ++c) {
                float pr = r[c] * inv;
                bool fg = (c == lab);
                float err = fg ? (1.f - pr) : pr;
                int idx = __float2int_rn(err * (float)(NBINS - 1));
                idx = idx < 0 ? 0 : (idx > NBINS - 1 ? NBINS - 1 : idx);
                // bin-0 non-fg entries have zero loss weight and affect no
                // higher-level cumulative count: skip their atomic.
                if (idx != 0 || fg)
                    atomicAdd(&hist[c * NBINS + idx], fg ? 0x10001u : 1u);
            }
        }
    }
    __syncthreads();
    // flush LDS histogram into this block's group partials (device atomics)
    int g = blockIdx.x & (NGROUPS - 1);
    int* nG = nGlob + (size_t)g * HISTWORDS;
    int* fG = fGlob + (size_t)g * HISTWORDS;
    for (int i = tid; i < HISTWORDS; i += 1024) {
        unsigned int w = hist[i];
        unsigned int n = w & 0xFFFFu;
        unsigned int f = w >> 16;
        if (n) atomicAdd(&nG[i], (int)n);
        if (f) atomicAdd(&fG[i], (int)f);
    }
}

// K2: single block, 16 waves. Wave w handles classes w, w+16 (descending-bin
// shfl scan + Jaccard integral), then thread 0 averages present classes.
__global__ __launch_bounds__(1024) void k2_scan(
    const int* __restrict__ nGlob, const int* __restrict__ fGlob,
    float* __restrict__ out)
{
    __shared__ float resL[32];
    __shared__ float gL[32];
    int tid = threadIdx.x;
    int wave = tid >> 6;
    int lane = tid & 63;

    for (int c = wave; c < C_CLASSES; c += 16) {
        const int PER = NBINS / 64;   // 12
        int nl[PER], fl[PER];
        int totN = 0, totF = 0;
#pragma unroll
        for (int i = 0; i < PER; ++i) {
            int j = lane * PER + i;            // ascending j = descending error
            int bin = NBINS - 1 - j;
            int pos = c * NBINS + bin;
            int n = 0, f = 0;
#pragma unroll
            for (int g = 0; g < NGROUPS; ++g) {
                n += nGlob[g * HISTWORDS + pos];
                f += fGlob[g * HISTWORDS + pos];
            }
            nl[i] = n; fl[i] = f; totN += n; totF += f;
        }
        // inclusive scan of lane totals across the wave
        int incN = totN, incF = totF;
        for (int off = 1; off < 64; off <<= 1) {
            int tn = __shfl_up(incN, off);
            int tf = __shfl_up(incF, off);
            if (lane >= off) { incN += tn; incF += tf; }
        }
        int G = __shfl(incF, 63);
        double loss = 0.0;
        if (G > 0) {
            int cumN = incN - totN;            // exclusive prefix for this lane
            int cumF = incF - totF;
            double dG = (double)G;
            double Jb = 1.0 - (dG - (double)cumF) / (dG + (double)cumN - (double)cumF);
#pragma unroll
            for (int i = 0; i < PER; ++i) {
                int bin = NBINS - 1 - (lane * PER + i);
                cumN += nl[i]; cumF += fl[i];
                double Ja = 1.0 - (dG - (double)cumF) / (dG + (double)cumN - (double)cumF);
                loss += ((double)bin / (double)(NBINS - 1)) * (Ja - Jb);
                Jb = Ja;
            }
        }
        for (int off = 32; off > 0; off >>= 1)
            loss += __shfl_down(loss, off);
        if (lane == 0) { resL[c] = (float)loss; gL[c] = (float)G; }
    }
    __syncthreads();
    if (tid == 0) {
        float s = 0.f, cnt = 0.f;
        for (int c = 0; c < C_CLASSES; ++c)
            if (gL[c] > 0.f) { s += resL[c]; cnt += 1.f; }
        out[0] = s / fmaxf(cnt, 1.f);
    }
}

extern "C" void kernel_launch(void* const* d_in, const int* in_sizes, int n_in,
                              void* d_out, int out_size, void* d_ws, size_t ws_size,
                              hipStream_t stream)
{
    const float* x = (const float*)d_in[0];
    const int* labels = (const int*)d_in[1];
    float* out = (float*)d_out;
    int P = in_sizes[1];   // B*H*W = 2,097,152

    const size_t partWords = (size_t)NGROUPS * HISTWORDS;  // 116,736
    int* nGlob = (int*)d_ws;
    int* fGlob = nGlob + partWords;

    hipMemsetAsync(d_ws, 0, 2 * partWords * sizeof(int), stream);

    const int NBLOCKS = 512;
    int pixPerBlk = (P + NBLOCKS - 1) / NBLOCKS;
    pixPerBlk = ((pixPerBlk + 1023) / 1024) * 1024;

    k1_hist<<<dim3(NBLOCKS), dim3(1024), 0, stream>>>(x, labels, nGlob, fGlob, P, pixPerBlk);
    k2_scan<<<dim3(1), dim3(1024), 0, stream>>>(nGlob, fGlob, out);
}